// Round 2
// baseline (1588.511 us; speedup 1.0000x reference)
//
#include <hip/hip_runtime.h>
#include <hip/hip_fp16.h>

typedef _Float16 f16x2 __attribute__((ext_vector_type(2)));
typedef _Float16 f16x8 __attribute__((ext_vector_type(8)));

#define TS  512
#define HID 256
#define G3  768
#define EMB 128

__device__ __forceinline__ float sigmoidf_(float x){ return 1.0f/(1.0f+__expf(-x)); }
__device__ __forceinline__ float tanhf_(float x){
  float e = __expf(-2.0f*fabsf(x));
  float t = (1.0f-e)/(1.0f+e);
  return copysignf(t,x);
}

// K1: xi0[t][j] = bih0[j] + sum_k Wih0[j][k] * emb[x[t,511]][k]
// 64 blocks x 256 threads, 8 timesteps per block (amortizes W reads 8x).
__global__ __launch_bounds__(256) void xi0_kernel(const int* __restrict__ x,
    const float* __restrict__ emb_tab, const float* __restrict__ Wih0,
    const float* __restrict__ bih0, float* __restrict__ xi0)
{
  __shared__ float embs[8][EMB];
  __shared__ int idx8[8];
  int tid = threadIdx.x;
  int t0  = blockIdx.x * 8;
  if (tid < 8) idx8[tid] = x[(t0 + tid)*512 + 511];
  __syncthreads();
  for (int i = tid; i < 8*EMB; i += 256){
    int q = i >> 7, r = i & 127;
    embs[q][r] = emb_tab[(long)idx8[q]*EMB + r];
  }
  __syncthreads();
  for (int g = 0; g < 3; g++){
    int j = g*256 + tid;
    float b = bih0[j];
    float acc[8];
    #pragma unroll
    for (int u=0;u<8;u++) acc[u]=b;
    const float4* wrow = (const float4*)(Wih0 + (long)j*EMB);
    #pragma unroll 8
    for (int m=0;m<EMB/4;m++){
      float4 w = wrow[m];
      #pragma unroll
      for (int u=0;u<8;u++){
        acc[u] += w.x*embs[u][4*m+0] + w.y*embs[u][4*m+1]
                + w.z*embs[u][4*m+2] + w.w*embs[u][4*m+3];
      }
    }
    #pragma unroll
    for (int u=0;u<8;u++) xi0[(long)(t0+u)*G3 + j] = acc[u];
  }
}

// K3: xi1[t][j] = bih1[j] + sum_k Wih1[j][k] * h1[t][k]
__global__ __launch_bounds__(256) void xi1_kernel(const float* __restrict__ h1,
    const float* __restrict__ Wih1, const float* __restrict__ bih1,
    float* __restrict__ xi1)
{
  __shared__ float hs[8][HID];
  int tid = threadIdx.x;
  int t0  = blockIdx.x * 8;
  for (int i = tid; i < 8*HID; i += 256){
    int q = i >> 8, r = i & 255;
    hs[q][r] = h1[(long)(t0+q)*HID + r];
  }
  __syncthreads();
  for (int g = 0; g < 3; g++){
    int j = g*256 + tid;
    float b = bih1[j];
    float acc[8];
    #pragma unroll
    for (int u=0;u<8;u++) acc[u]=b;
    const float4* wrow = (const float4*)(Wih1 + (long)j*HID);
    #pragma unroll 4
    for (int m=0;m<HID/4;m++){
      float4 w = wrow[m];
      #pragma unroll
      for (int u=0;u<8;u++){
        acc[u] += w.x*hs[u][4*m+0] + w.y*hs[u][4*m+1]
                + w.z*hs[u][4*m+2] + w.w*hs[u][4*m+3];
      }
    }
    #pragma unroll
    for (int u=0;u<8;u++) xi1[(long)(t0+u)*G3 + j] = acc[u];
  }
}

// K2/K4: sequential GRU recurrence for ONE sequence.
// 1 block x 768 threads; thread j holds row j of Whh as 128 packed f16 pairs
// in VGPRs. h state broadcast via LDS (same-address ds_read_b128 = free).
// __launch_bounds__(768, 3): we run exactly 12 waves = 3 waves/EU on one CU;
// this raises the VGPR cap to ~168 so the 128-VGPR weight row stays register-
// resident (default target was 6 waves/EU -> 84 VGPRs -> w[] spilled to
// scratch -> 710 us L2-bound; see round-1 counters).
__global__ __launch_bounds__(768, 3) void gru_rec_kernel(const float* __restrict__ Whh,
    const float* __restrict__ bhh, const float* __restrict__ xi,
    float* __restrict__ hout)
{
  __shared__ f16x8 hsh[HID/8];   // 256 f16 = 32 x 16B
  __shared__ float h32[HID];
  __shared__ float gh[G3];
  int tid = threadIdx.x;         // == output row j

  // one-time: load + convert weight row j into registers (128 VGPRs of f16x2)
  f16x2 w[HID/2];
  {
    const float4* wrow = (const float4*)(Whh + (long)tid*HID);
    #pragma unroll
    for (int m=0;m<HID/4;m++){
      float4 v = wrow[m];
      f16x2 a; a.x=(_Float16)v.x; a.y=(_Float16)v.y;
      f16x2 b; b.x=(_Float16)v.z; b.y=(_Float16)v.w;
      w[2*m+0]=a; w[2*m+1]=b;
    }
  }
  float breg = bhh[tid];

  if (tid < HID/8){ f16x8 z = {0,0,0,0,0,0,0,0}; hsh[tid]=z; }
  if (tid < HID) h32[tid] = 0.0f;
  __syncthreads();

  // software-prefetched xi for step t (hidden behind the dot phase)
  float xiv_n = (tid < 512) ? xi[tid]       : 0.0f;
  float xnn   = (tid < HID) ? xi[512 + tid] : 0.0f;

  for (int t = 0; t < TS; t++){
    float xiv = xiv_n;
    float xnc = xnn;
    if (t + 1 < TS){
      xiv_n = (tid < 512) ? xi[(long)(t+1)*G3 + tid]       : 0.0f;
      xnn   = (tid < HID) ? xi[(long)(t+1)*G3 + 512 + tid] : 0.0f;
    }
    float acc0 = breg + xiv;   // j>=512 (n-gate): xiv==0, xn added after r*hn
    float acc1 = 0.0f;
    #pragma unroll
    for (int m=0;m<HID/8;m++){
      f16x8 hv = hsh[m];
      acc0 = __builtin_amdgcn_fdot2(w[4*m+0], __builtin_shufflevector(hv,hv,0,1), acc0, false);
      acc1 = __builtin_amdgcn_fdot2(w[4*m+1], __builtin_shufflevector(hv,hv,2,3), acc1, false);
      acc0 = __builtin_amdgcn_fdot2(w[4*m+2], __builtin_shufflevector(hv,hv,4,5), acc0, false);
      acc1 = __builtin_amdgcn_fdot2(w[4*m+3], __builtin_shufflevector(hv,hv,6,7), acc1, false);
    }
    gh[tid] = acc0 + acc1;
    __syncthreads();

    if (tid < HID){
      float r  = sigmoidf_(gh[tid]);
      float z  = sigmoidf_(gh[HID + tid]);
      float hn = gh[2*HID + tid];
      float n  = tanhf_(xnc + r*hn);
      float hnew = (1.0f - z)*n + z*h32[tid];
      h32[tid] = hnew;
      hout[(long)t*HID + tid] = hnew;          // fp32 trace for next stage
      float partner = __shfl_xor(hnew, 1, 64); // pack pairs for f16 state
      if ((tid & 1) == 0){
        f16x2 p; p.x = (_Float16)hnew; p.y = (_Float16)partner;
        ((f16x2*)hsh)[tid >> 1] = p;
      }
    }
    __syncthreads();
  }
}

// K5: logits[t][c] = b_out[c] + sum_i h2[t][i] * W_out[c][i]
__global__ __launch_bounds__(1024) void logits_kernel(const float* __restrict__ h2,
    const float* __restrict__ Wout, const float* __restrict__ bout,
    float* __restrict__ out)
{
  __shared__ __align__(16) float wsm[2*HID];
  __shared__ float bs[2];
  int tid = threadIdx.x;
  if (tid < 2*HID) wsm[tid] = Wout[tid];
  if (tid < 2)     bs[tid]  = bout[tid];
  __syncthreads();
  int t = tid >> 1, c = tid & 1;
  const float4* hr = (const float4*)(h2 + (long)t*HID);
  const float4* wr = (const float4*)(wsm + c*HID);
  float acc = bs[c];
  #pragma unroll 8
  for (int m=0;m<HID/4;m++){
    float4 h = hr[m]; float4 wv = wr[m];
    acc += h.x*wv.x + h.y*wv.y + h.z*wv.z + h.w*wv.w;
  }
  out[tid] = acc;
}

extern "C" void kernel_launch(void* const* d_in, const int* in_sizes, int n_in,
                              void* d_out, int out_size, void* d_ws, size_t ws_size,
                              hipStream_t stream)
{
  const int*   x    = (const int*)  d_in[0];
  const float* emb  = (const float*)d_in[1];
  const float* Wih0 = (const float*)d_in[2];
  const float* Whh0 = (const float*)d_in[3];
  const float* bih0 = (const float*)d_in[4];
  const float* bhh0 = (const float*)d_in[5];
  const float* Wih1 = (const float*)d_in[6];
  const float* Whh1 = (const float*)d_in[7];
  const float* bih1 = (const float*)d_in[8];
  const float* bhh1 = (const float*)d_in[9];
  const float* Wout = (const float*)d_in[10];
  const float* bout = (const float*)d_in[11];
  float* out = (float*)d_out;

  char* ws = (char*)d_ws;
  float* xi0 = (float*)(ws);                                  // 512*768 f32
  float* xi1 = (float*)(ws + (size_t)TS*G3*4);                // 512*768 f32
  float* h1  = (float*)(ws + (size_t)2*TS*G3*4);              // 512*256 f32
  float* h2  = (float*)(ws + (size_t)2*TS*G3*4 + (size_t)TS*HID*4);

  xi0_kernel   <<<64, 256, 0, stream>>>(x, emb, Wih0, bih0, xi0);
  gru_rec_kernel<<<1, 768, 0, stream>>>(Whh0, bhh0, xi0, h1);
  xi1_kernel   <<<64, 256, 0, stream>>>(h1, Wih1, bih1, xi1);
  gru_rec_kernel<<<1, 768, 0, stream>>>(Whh1, bhh1, xi1, h2);
  logits_kernel<<<1, 1024, 0, stream>>>(h2, Wout, bout, out);
}

// Round 3
// 1584.500 us; speedup vs baseline: 1.0025x; 1.0025x over previous
//
#include <hip/hip_runtime.h>
#include <hip/hip_fp16.h>

typedef _Float16 f16x2 __attribute__((ext_vector_type(2)));
typedef _Float16 f16x8 __attribute__((ext_vector_type(8)));

#define TS  512
#define HID 256
#define G3  768
#define EMB 128

__device__ __forceinline__ float sigmoidf_(float x){ return 1.0f/(1.0f+__expf(-x)); }
__device__ __forceinline__ float tanhf_(float x){
  float e = __expf(-2.0f*fabsf(x));
  float t = (1.0f-e)/(1.0f+e);
  return copysignf(t,x);
}

// K1: xi0[t][j] = bih0[j] + sum_k Wih0[j][k] * emb[x[t,511]][k]
// 64 blocks x 256 threads, 8 timesteps per block (amortizes W reads 8x).
__global__ __launch_bounds__(256) void xi0_kernel(const int* __restrict__ x,
    const float* __restrict__ emb_tab, const float* __restrict__ Wih0,
    const float* __restrict__ bih0, float* __restrict__ xi0)
{
  __shared__ float embs[8][EMB];
  __shared__ int idx8[8];
  int tid = threadIdx.x;
  int t0  = blockIdx.x * 8;
  if (tid < 8) idx8[tid] = x[(t0 + tid)*512 + 511];
  __syncthreads();
  for (int i = tid; i < 8*EMB; i += 256){
    int q = i >> 7, r = i & 127;
    embs[q][r] = emb_tab[(long)idx8[q]*EMB + r];
  }
  __syncthreads();
  for (int g = 0; g < 3; g++){
    int j = g*256 + tid;
    float b = bih0[j];
    float acc[8];
    #pragma unroll
    for (int u=0;u<8;u++) acc[u]=b;
    const float4* wrow = (const float4*)(Wih0 + (long)j*EMB);
    #pragma unroll 8
    for (int m=0;m<EMB/4;m++){
      float4 w = wrow[m];
      #pragma unroll
      for (int u=0;u<8;u++){
        acc[u] += w.x*embs[u][4*m+0] + w.y*embs[u][4*m+1]
                + w.z*embs[u][4*m+2] + w.w*embs[u][4*m+3];
      }
    }
    #pragma unroll
    for (int u=0;u<8;u++) xi0[(long)(t0+u)*G3 + j] = acc[u];
  }
}

// K3: xi1[t][j] = bih1[j] + sum_k Wih1[j][k] * h1[t][k]
__global__ __launch_bounds__(256) void xi1_kernel(const float* __restrict__ h1,
    const float* __restrict__ Wih1, const float* __restrict__ bih1,
    float* __restrict__ xi1)
{
  __shared__ float hs[8][HID];
  int tid = threadIdx.x;
  int t0  = blockIdx.x * 8;
  for (int i = tid; i < 8*HID; i += 256){
    int q = i >> 8, r = i & 255;
    hs[q][r] = h1[(long)(t0+q)*HID + r];
  }
  __syncthreads();
  for (int g = 0; g < 3; g++){
    int j = g*256 + tid;
    float b = bih1[j];
    float acc[8];
    #pragma unroll
    for (int u=0;u<8;u++) acc[u]=b;
    const float4* wrow = (const float4*)(Wih1 + (long)j*HID);
    #pragma unroll 4
    for (int m=0;m<HID/4;m++){
      float4 w = wrow[m];
      #pragma unroll
      for (int u=0;u<8;u++){
        acc[u] += w.x*hs[u][4*m+0] + w.y*hs[u][4*m+1]
                + w.z*hs[u][4*m+2] + w.w*hs[u][4*m+3];
      }
    }
    #pragma unroll
    for (int u=0;u<8;u++) xi1[(long)(t0+u)*G3 + j] = acc[u];
  }
}

// K2/K4: sequential GRU recurrence for ONE sequence.
// 1 block x 768 threads; thread j holds row j of Whh as 128 packed f16 pairs
// in VGPRs. h state broadcast via LDS (same-address ds_read_b128 = free).
//
// Occupancy MUST be pinned to exactly 12 waves = 3 waves/EU so the 128-VGPR
// weight array stays register-resident (384 KB = 75% of the CU's VGPR file).
// __launch_bounds__(768,3) only sets the MIN waves/EU and was ignored
// (VGPR_Count stayed 84 -> w[] spilled to scratch -> 710 us L2-bound, rounds
// 1-2). amdgpu_waves_per_eu(3,3) pins min=max, budget = 512/3 ~ 170 regs.
__global__
__attribute__((amdgpu_flat_work_group_size(768,768), amdgpu_waves_per_eu(3,3)))
void gru_rec_kernel(const float* __restrict__ Whh,
    const float* __restrict__ bhh, const float* __restrict__ xi,
    float* __restrict__ hout)
{
  __shared__ f16x8 hsh[HID/8];   // 256 f16 = 32 x 16B
  __shared__ float h32[HID];
  __shared__ float gh[G3];
  int tid = threadIdx.x;         // == output row j

  // one-time: load + convert weight row j into registers (128 VGPRs of f16x2)
  f16x2 w[HID/2];
  {
    const float4* wrow = (const float4*)(Whh + (long)tid*HID);
    #pragma unroll
    for (int m=0;m<HID/4;m++){
      float4 v = wrow[m];
      f16x2 a; a.x=(_Float16)v.x; a.y=(_Float16)v.y;
      f16x2 b; b.x=(_Float16)v.z; b.y=(_Float16)v.w;
      w[2*m+0]=a; w[2*m+1]=b;
    }
  }
  float breg = bhh[tid];

  if (tid < HID/8){ f16x8 z = {0,0,0,0,0,0,0,0}; hsh[tid]=z; }
  if (tid < HID) h32[tid] = 0.0f;
  __syncthreads();

  // software-prefetched xi for step t (hidden behind the dot phase)
  float xiv_n = (tid < 512) ? xi[tid]       : 0.0f;
  float xnn   = (tid < HID) ? xi[512 + tid] : 0.0f;

  for (int t = 0; t < TS; t++){
    float xiv = xiv_n;
    float xnc = xnn;
    if (t + 1 < TS){
      xiv_n = (tid < 512) ? xi[(long)(t+1)*G3 + tid]       : 0.0f;
      xnn   = (tid < HID) ? xi[(long)(t+1)*G3 + 512 + tid] : 0.0f;
    }
    float acc0 = breg + xiv;   // j>=512 (n-gate): xiv==0, xn added after r*hn
    float acc1 = 0.0f;
    #pragma unroll
    for (int m=0;m<HID/8;m++){
      f16x8 hv = hsh[m];
      acc0 = __builtin_amdgcn_fdot2(w[4*m+0], __builtin_shufflevector(hv,hv,0,1), acc0, false);
      acc1 = __builtin_amdgcn_fdot2(w[4*m+1], __builtin_shufflevector(hv,hv,2,3), acc1, false);
      acc0 = __builtin_amdgcn_fdot2(w[4*m+2], __builtin_shufflevector(hv,hv,4,5), acc0, false);
      acc1 = __builtin_amdgcn_fdot2(w[4*m+3], __builtin_shufflevector(hv,hv,6,7), acc1, false);
    }
    gh[tid] = acc0 + acc1;
    __syncthreads();

    if (tid < HID){
      float r  = sigmoidf_(gh[tid]);
      float z  = sigmoidf_(gh[HID + tid]);
      float hn = gh[2*HID + tid];
      float n  = tanhf_(xnc + r*hn);
      float hnew = (1.0f - z)*n + z*h32[tid];
      h32[tid] = hnew;
      hout[(long)t*HID + tid] = hnew;          // fp32 trace for next stage
      float partner = __shfl_xor(hnew, 1, 64); // pack pairs for f16 state
      if ((tid & 1) == 0){
        f16x2 p; p.x = (_Float16)hnew; p.y = (_Float16)partner;
        ((f16x2*)hsh)[tid >> 1] = p;
      }
    }
    __syncthreads();
  }
}

// K5: logits[t][c] = b_out[c] + sum_i h2[t][i] * W_out[c][i]
__global__ __launch_bounds__(1024) void logits_kernel(const float* __restrict__ h2,
    const float* __restrict__ Wout, const float* __restrict__ bout,
    float* __restrict__ out)
{
  __shared__ __align__(16) float wsm[2*HID];
  __shared__ float bs[2];
  int tid = threadIdx.x;
  if (tid < 2*HID) wsm[tid] = Wout[tid];
  if (tid < 2)     bs[tid]  = bout[tid];
  __syncthreads();
  int t = tid >> 1, c = tid & 1;
  const float4* hr = (const float4*)(h2 + (long)t*HID);
  const float4* wr = (const float4*)(wsm + c*HID);
  float acc = bs[c];
  #pragma unroll 8
  for (int m=0;m<HID/4;m++){
    float4 h = hr[m]; float4 wv = wr[m];
    acc += h.x*wv.x + h.y*wv.y + h.z*wv.z + h.w*wv.w;
  }
  out[tid] = acc;
}

extern "C" void kernel_launch(void* const* d_in, const int* in_sizes, int n_in,
                              void* d_out, int out_size, void* d_ws, size_t ws_size,
                              hipStream_t stream)
{
  const int*   x    = (const int*)  d_in[0];
  const float* emb  = (const float*)d_in[1];
  const float* Wih0 = (const float*)d_in[2];
  const float* Whh0 = (const float*)d_in[3];
  const float* bih0 = (const float*)d_in[4];
  const float* bhh0 = (const float*)d_in[5];
  const float* Wih1 = (const float*)d_in[6];
  const float* Whh1 = (const float*)d_in[7];
  const float* bih1 = (const float*)d_in[8];
  const float* bhh1 = (const float*)d_in[9];
  const float* Wout = (const float*)d_in[10];
  const float* bout = (const float*)d_in[11];
  float* out = (float*)d_out;

  char* ws = (char*)d_ws;
  float* xi0 = (float*)(ws);                                  // 512*768 f32
  float* xi1 = (float*)(ws + (size_t)TS*G3*4);                // 512*768 f32
  float* h1  = (float*)(ws + (size_t)2*TS*G3*4);              // 512*256 f32
  float* h2  = (float*)(ws + (size_t)2*TS*G3*4 + (size_t)TS*HID*4);

  xi0_kernel   <<<64, 256, 0, stream>>>(x, emb, Wih0, bih0, xi0);
  gru_rec_kernel<<<1, 768, 0, stream>>>(Whh0, bhh0, xi0, h1);
  xi1_kernel   <<<64, 256, 0, stream>>>(h1, Wih1, bih1, xi1);
  gru_rec_kernel<<<1, 768, 0, stream>>>(Whh1, bhh1, xi1, h2);
  logits_kernel<<<1, 1024, 0, stream>>>(h2, Wout, bout, out);
}

// Round 4
// 1582.125 us; speedup vs baseline: 1.0040x; 1.0015x over previous
//
#include <hip/hip_runtime.h>
#include <hip/hip_fp16.h>

typedef _Float16 f16x2 __attribute__((ext_vector_type(2)));
typedef _Float16 f16x8 __attribute__((ext_vector_type(8)));

#define TS  512
#define HID 256
#define G3  768
#define EMB 128

__device__ __forceinline__ float sigmoidf_(float x){ return 1.0f/(1.0f+__expf(-x)); }
__device__ __forceinline__ float tanhf_(float x){
  float e = __expf(-2.0f*fabsf(x));
  float t = (1.0f-e)/(1.0f+e);
  return copysignf(t,x);
}

// K1: xi0[t][j] = bih0[j] + sum_k Wih0[j][k] * emb[x[t,511]][k]
__global__ __launch_bounds__(256) void xi0_kernel(const int* __restrict__ x,
    const float* __restrict__ emb_tab, const float* __restrict__ Wih0,
    const float* __restrict__ bih0, float* __restrict__ xi0)
{
  __shared__ float embs[8][EMB];
  __shared__ int idx8[8];
  int tid = threadIdx.x;
  int t0  = blockIdx.x * 8;
  if (tid < 8) idx8[tid] = x[(t0 + tid)*512 + 511];
  __syncthreads();
  for (int i = tid; i < 8*EMB; i += 256){
    int q = i >> 7, r = i & 127;
    embs[q][r] = emb_tab[(long)idx8[q]*EMB + r];
  }
  __syncthreads();
  for (int g = 0; g < 3; g++){
    int j = g*256 + tid;
    float b = bih0[j];
    float acc[8];
    #pragma unroll
    for (int u=0;u<8;u++) acc[u]=b;
    const float4* wrow = (const float4*)(Wih0 + (long)j*EMB);
    #pragma unroll 8
    for (int m=0;m<EMB/4;m++){
      float4 w = wrow[m];
      #pragma unroll
      for (int u=0;u<8;u++){
        acc[u] += w.x*embs[u][4*m+0] + w.y*embs[u][4*m+1]
                + w.z*embs[u][4*m+2] + w.w*embs[u][4*m+3];
      }
    }
    #pragma unroll
    for (int u=0;u<8;u++) xi0[(long)(t0+u)*G3 + j] = acc[u];
  }
}

// K3: xi1[t][j] = bih1[j] + sum_k Wih1[j][k] * h1[t][k]
__global__ __launch_bounds__(256) void xi1_kernel(const float* __restrict__ h1,
    const float* __restrict__ Wih1, const float* __restrict__ bih1,
    float* __restrict__ xi1)
{
  __shared__ float hs[8][HID];
  int tid = threadIdx.x;
  int t0  = blockIdx.x * 8;
  for (int i = tid; i < 8*HID; i += 256){
    int q = i >> 8, r = i & 255;
    hs[q][r] = h1[(long)(t0+q)*HID + r];
  }
  __syncthreads();
  for (int g = 0; g < 3; g++){
    int j = g*256 + tid;
    float b = bih1[j];
    float acc[8];
    #pragma unroll
    for (int u=0;u<8;u++) acc[u]=b;
    const float4* wrow = (const float4*)(Wih1 + (long)j*HID);
    #pragma unroll 4
    for (int m=0;m<HID/4;m++){
      float4 w = wrow[m];
      #pragma unroll
      for (int u=0;u<8;u++){
        acc[u] += w.x*hs[u][4*m+0] + w.y*hs[u][4*m+1]
                + w.z*hs[u][4*m+2] + w.w*hs[u][4*m+3];
      }
    }
    #pragma unroll
    for (int u=0;u<8;u++) xi1[(long)(t0+u)*G3 + j] = acc[u];
  }
}

// K2/K4: sequential GRU recurrence for ONE sequence.
// 1 block x 768 threads; thread j holds row j of Whh as 32 named f16x8 SSA
// vector values (128 VGPRs). Rounds 1-3 showed a C array `f16x2 w[128]` is
// NEVER promoted out of its alloca (VGPR_Count pinned at 84 across all
// occupancy hints -> scratch-L2 bound at 710us). Named ext-vector variables
// with parse-time-constant shuffle indices cannot be demoted to scratch by
// the frontend; the allocator now sees the true pressure. launch_bounds
// (768,3) = min 3 waves/EU -> VGPR cap ~170, enough for 128 wregs + ~40.
#define WCHUNKS(X) X(0) X(1) X(2) X(3) X(4) X(5) X(6) X(7) \
  X(8) X(9) X(10) X(11) X(12) X(13) X(14) X(15) \
  X(16) X(17) X(18) X(19) X(20) X(21) X(22) X(23) \
  X(24) X(25) X(26) X(27) X(28) X(29) X(30) X(31)

__global__ __launch_bounds__(768, 3)
void gru_rec_kernel(const float* __restrict__ Whh,
    const float* __restrict__ bhh, const float* __restrict__ xi,
    float* __restrict__ hout)
{
  __shared__ f16x8 hsh[HID/8];   // 256 f16 state, broadcast-read by all
  __shared__ float h32[HID];
  __shared__ float gh[G3];
  int tid = threadIdx.x;         // == output row j

#define WDECL(I) f16x8 w##I;
  WCHUNKS(WDECL)

  {
    const float4* wrow = (const float4*)(Whh + (long)tid*HID);
#define WLOAD(I) { float4 va = wrow[2*(I)]; float4 vb = wrow[2*(I)+1]; \
    w##I = (f16x8){(_Float16)va.x,(_Float16)va.y,(_Float16)va.z,(_Float16)va.w, \
                   (_Float16)vb.x,(_Float16)vb.y,(_Float16)vb.z,(_Float16)vb.w}; }
    WCHUNKS(WLOAD)
  }
  float breg = bhh[tid];

  if (tid < HID/8){ f16x8 z = {0,0,0,0,0,0,0,0}; hsh[tid]=z; }
  if (tid < HID) h32[tid] = 0.0f;
  __syncthreads();

  // software-prefetched xi for step t (hidden behind the dot phase)
  float xiv_n = (tid < 512) ? xi[tid]       : 0.0f;
  float xnn   = (tid < HID) ? xi[512 + tid] : 0.0f;

  for (int t = 0; t < TS; t++){
    float xiv = xiv_n;
    float xnc = xnn;
    if (t + 1 < TS){
      xiv_n = (tid < 512) ? xi[(long)(t+1)*G3 + tid]       : 0.0f;
      xnn   = (tid < HID) ? xi[(long)(t+1)*G3 + 512 + tid] : 0.0f;
    }
    float acc0 = breg + xiv;   // j>=512 (n-gate): xiv==0, xn added after r*hn
    float acc1 = 0.0f;
#define WDOT(I) { f16x8 hv = hsh[I]; \
    acc0 = __builtin_amdgcn_fdot2(__builtin_shufflevector(w##I,w##I,0,1), \
                                  __builtin_shufflevector(hv,hv,0,1), acc0, false); \
    acc1 = __builtin_amdgcn_fdot2(__builtin_shufflevector(w##I,w##I,2,3), \
                                  __builtin_shufflevector(hv,hv,2,3), acc1, false); \
    acc0 = __builtin_amdgcn_fdot2(__builtin_shufflevector(w##I,w##I,4,5), \
                                  __builtin_shufflevector(hv,hv,4,5), acc0, false); \
    acc1 = __builtin_amdgcn_fdot2(__builtin_shufflevector(w##I,w##I,6,7), \
                                  __builtin_shufflevector(hv,hv,6,7), acc1, false); }
    WCHUNKS(WDOT)
    gh[tid] = acc0 + acc1;
    __syncthreads();

    if (tid < HID){
      float r  = sigmoidf_(gh[tid]);
      float z  = sigmoidf_(gh[HID + tid]);
      float hn = gh[2*HID + tid];
      float n  = tanhf_(xnc + r*hn);
      float hnew = (1.0f - z)*n + z*h32[tid];
      h32[tid] = hnew;
      hout[(long)t*HID + tid] = hnew;          // fp32 trace for next stage
      float partner = __shfl_xor(hnew, 1, 64); // pack pairs for f16 state
      if ((tid & 1) == 0){
        f16x2 p; p.x = (_Float16)hnew; p.y = (_Float16)partner;
        ((f16x2*)hsh)[tid >> 1] = p;
      }
    }
    __syncthreads();
  }
}

// K5: logits[t][c] = b_out[c] + sum_i h2[t][i] * W_out[c][i]
__global__ __launch_bounds__(1024) void logits_kernel(const float* __restrict__ h2,
    const float* __restrict__ Wout, const float* __restrict__ bout,
    float* __restrict__ out)
{
  __shared__ __align__(16) float wsm[2*HID];
  __shared__ float bs[2];
  int tid = threadIdx.x;
  if (tid < 2*HID) wsm[tid] = Wout[tid];
  if (tid < 2)     bs[tid]  = bout[tid];
  __syncthreads();
  int t = tid >> 1, c = tid & 1;
  const float4* hr = (const float4*)(h2 + (long)t*HID);
  const float4* wr = (const float4*)(wsm + c*HID);
  float acc = bs[c];
  #pragma unroll 8
  for (int m=0;m<HID/4;m++){
    float4 h = hr[m]; float4 wv = wr[m];
    acc += h.x*wv.x + h.y*wv.y + h.z*wv.z + h.w*wv.w;
  }
  out[tid] = acc;
}

extern "C" void kernel_launch(void* const* d_in, const int* in_sizes, int n_in,
                              void* d_out, int out_size, void* d_ws, size_t ws_size,
                              hipStream_t stream)
{
  const int*   x    = (const int*)  d_in[0];
  const float* emb  = (const float*)d_in[1];
  const float* Wih0 = (const float*)d_in[2];
  const float* Whh0 = (const float*)d_in[3];
  const float* bih0 = (const float*)d_in[4];
  const float* bhh0 = (const float*)d_in[5];
  const float* Wih1 = (const float*)d_in[6];
  const float* Whh1 = (const float*)d_in[7];
  const float* bih1 = (const float*)d_in[8];
  const float* bhh1 = (const float*)d_in[9];
  const float* Wout = (const float*)d_in[10];
  const float* bout = (const float*)d_in[11];
  float* out = (float*)d_out;

  char* ws = (char*)d_ws;
  float* xi0 = (float*)(ws);                                  // 512*768 f32
  float* xi1 = (float*)(ws + (size_t)TS*G3*4);                // 512*768 f32
  float* h1  = (float*)(ws + (size_t)2*TS*G3*4);              // 512*256 f32
  float* h2  = (float*)(ws + (size_t)2*TS*G3*4 + (size_t)TS*HID*4);

  xi0_kernel   <<<64, 256, 0, stream>>>(x, emb, Wih0, bih0, xi0);
  gru_rec_kernel<<<1, 768, 0, stream>>>(Whh0, bhh0, xi0, h1);
  xi1_kernel   <<<64, 256, 0, stream>>>(h1, Wih1, bih1, xi1);
  gru_rec_kernel<<<1, 768, 0, stream>>>(Whh1, bhh1, xi1, h2);
  logits_kernel<<<1, 1024, 0, stream>>>(h2, Wout, bout, out);
}